// Round 4
// baseline (446.926 us; speedup 1.0000x reference)
//
#include <hip/hip_runtime.h>
#include <hip/hip_fp16.h>

#define DIM 128

// ---------------- graph build ----------------
__global__ void k_count(const int* __restrict__ col, int E, int* __restrict__ cnt){
  int i = blockIdx.x*blockDim.x + threadIdx.x;
  if (i < E) atomicAdd(&cnt[col[i]], 1);
}

__global__ void k_scan1(const int* __restrict__ cnt, int* __restrict__ off,
                        int* __restrict__ bsum, int N){
  __shared__ int s[256];
  int i = blockIdx.x*256 + threadIdx.x;
  int v = (i < N) ? cnt[i] : 0;
  s[threadIdx.x] = v;
  __syncthreads();
  for (int d = 1; d < 256; d <<= 1){
    int t = (threadIdx.x >= d) ? s[threadIdx.x - d] : 0;
    __syncthreads();
    s[threadIdx.x] += t;
    __syncthreads();
  }
  if (i < N) off[i] = s[threadIdx.x] - v;       // exclusive within block
  if (threadIdx.x == 255) bsum[blockIdx.x] = s[255];
}

__global__ void k_scan2(int* __restrict__ bsum, int nb){
  __shared__ int s[512];
  int t = threadIdx.x;
  int v = (t < nb) ? bsum[t] : 0;
  s[t] = v;
  __syncthreads();
  for (int d = 1; d < 512; d <<= 1){
    int x = (t >= d) ? s[t - d] : 0;
    __syncthreads();
    s[t] += x;
    __syncthreads();
  }
  if (t < nb) bsum[t] = s[t] - v;               // exclusive block offsets
}

// finalize offsets, init cursor=off, compute dinv
__global__ void k_scan3(int* __restrict__ off, const int* __restrict__ bsum,
                        const int* __restrict__ cnt, int* __restrict__ cursor,
                        float* __restrict__ dinv, int N){
  int i = blockIdx.x*blockDim.x + threadIdx.x;
  if (i < N){
    int o = off[i] + bsum[i >> 8];
    off[i] = o;
    cursor[i] = o;
    dinv[i] = rsqrtf((float)(cnt[i] + 1));      // +1 self-loop
  }
}

// ---- shared gemm block: Yh[32 rows](fp16) = dinv * ((relu?)X @ W + addvec) ----
__device__ __forceinline__ void gemm_block(const float* __restrict__ X,
                                           const float* __restrict__ W,
                                           const float* __restrict__ addvec,
                                           const float* __restrict__ dinv,
                                           __half* __restrict__ Yh, int N, int doRelu,
                                           int gb, float (*Xs)[DIM], float (*Ws)[DIM]){
  int tid = threadIdx.x;
  int tx = tid & 31;            // 4 output cols: tx*4
  int ty = tid >> 5;            // 8 groups x 4 rows
  int rb = gb * 32;

  #pragma unroll
  for (int i = 0; i < 4; i++){
    int s = i*256 + tid;        // [0,1024) float4 slots
    int r = s >> 5, cc = (s & 31) * 4;
    float4 val = make_float4(0.f,0.f,0.f,0.f);
    if (rb + r < N) val = *(const float4*)(X + (size_t)(rb + r)*DIM + cc);
    if (doRelu){
      val.x = fmaxf(val.x,0.f); val.y = fmaxf(val.y,0.f);
      val.z = fmaxf(val.z,0.f); val.w = fmaxf(val.w,0.f);
    }
    *(float4*)(&Xs[r][cc]) = val;
  }

  float acc[4][4];
  #pragma unroll
  for (int r4 = 0; r4 < 4; r4++){ acc[r4][0]=0.f; acc[r4][1]=0.f; acc[r4][2]=0.f; acc[r4][3]=0.f; }

  for (int kc = 0; kc < DIM; kc += 32){
    __syncthreads();
    #pragma unroll
    for (int i = 0; i < 4; i++){
      int s = i*256 + tid;
      int r = s >> 5, cc = (s & 31) * 4;
      *(float4*)(&Ws[r][cc]) = *(const float4*)(W + (size_t)(kc + r)*DIM + cc);
    }
    __syncthreads();
    #pragma unroll 8
    for (int k = 0; k < 32; k++){
      float4 w4 = *(const float4*)(&Ws[k][tx*4]);
      #pragma unroll
      for (int r4 = 0; r4 < 4; r4++){
        float xv = Xs[ty*4 + r4][kc + k];
        acc[r4][0] += xv*w4.x; acc[r4][1] += xv*w4.y;
        acc[r4][2] += xv*w4.z; acc[r4][3] += xv*w4.w;
      }
    }
  }

  float4 av = make_float4(0.f,0.f,0.f,0.f);
  if (addvec) av = *(const float4*)(addvec + tx*4);
  #pragma unroll
  for (int r4 = 0; r4 < 4; r4++){
    int r = rb + ty*4 + r4;
    if (r < N){
      float dv = dinv[r];
      float ox = dv*(acc[r4][0] + av.x), oy = dv*(acc[r4][1] + av.y);
      float oz = dv*(acc[r4][2] + av.z), ow = dv*(acc[r4][3] + av.w);
      __half2 h01 = __floats2half2_rn(ox, oy);
      __half2 h23 = __floats2half2_rn(oz, ow);
      uint2 u = make_uint2(*(unsigned int*)&h01, *(unsigned int*)&h23);
      *(uint2*)(Yh + (size_t)r*DIM + tx*4) = u;
    }
  }
}

// ---- mega1: even blocks = gemm1 (posts@W1 -> xw1s), odd blocks = CSR scatter ----
__global__ __launch_bounds__(256) void k_mega1(const float* __restrict__ posts,
    const float* __restrict__ W1, const float* __restrict__ dinv,
    __half* __restrict__ xw1s, const int* __restrict__ row, const int* __restrict__ col,
    int E, int* __restrict__ cursor, int* __restrict__ csr_row, int N, int nG){
  __shared__ float Xs[32][DIM];
  __shared__ float Ws[32][DIM];
  int bid = blockIdx.x;
  if ((bid & 1) == 0){
    int g = bid >> 1;
    if (g < nG) gemm_block(posts, W1, nullptr, dinv, xw1s, N, 0, g, Xs, Ws);
  } else {
    int s = bid >> 1;
    int e = s*512 + threadIdx.x;
    if (e < E){
      int c = col[e];
      int pos = atomicAdd(&cursor[c], 1);
      csr_row[pos] = row[e];
    }
    e += 256;
    if (e < E){
      int c = col[e];
      int pos = atomicAdd(&cursor[c], 1);
      csr_row[pos] = row[e];
    }
  }
}

// ---- mega2: even blocks = gemm2 (relu(c1out)@W2a + cvec -> xw2s), odd = const-col fill ----
__global__ __launch_bounds__(256) void k_mega2(const float* __restrict__ c1out,
    const float* __restrict__ W2, const float* __restrict__ cvec,
    const float* __restrict__ dinv, __half* __restrict__ xw2s,
    const float* __restrict__ cpool, float* __restrict__ outp, int N, int nG, int nF){
  __shared__ float Xs[32][DIM];
  __shared__ float Ws[32][DIM];
  int bid = blockIdx.x;
  if ((bid & 1) == 0){
    int g = bid >> 1;
    if (g < nG) gemm_block(c1out, W2, cvec, dinv, xw2s, N, 1, g, Xs, Ws);
  } else {
    int f = bid >> 1;
    if (f >= nF) return;
    int total = N * 63;                         // float2 slots for cols 0..125
    #pragma unroll
    for (int i = 0; i < 8; i++){
      int w = f*2048 + i*256 + threadIdx.x;
      if (w < total){
        unsigned int r  = (unsigned int)w / 63u;
        unsigned int c2 = (unsigned int)w - r*63u;
        float2 val = *(const float2*)(cpool + c2*2);
        *(float2*)(outp + (size_t)r*254 + c2*2) = val;
      }
    }
  }
}

// ---- conv1 aggregate: one wave/node, 2 rows/wave via half-split, uint2 gathers ----
__global__ void k_conv1(const __half* __restrict__ xws, const int* __restrict__ csr_row,
                        const int* __restrict__ off, const int* __restrict__ cnt,
                        const float* __restrict__ dinv, const float* __restrict__ b,
                        float* __restrict__ out, int N){
  int wid  = (blockIdx.x*blockDim.x + threadIdx.x) >> 6;
  if (wid >= N) return;
  int lane = threadIdx.x & 63;
  int half = lane >> 5;
  int sl   = lane & 31;
  int v = wid;
  float dv = dinv[v];
  int o0 = off[v], total = cnt[v] + 1;          // virtual row 0 = self

  float ax = 0.f, ay = 0.f, az = 0.f, aw = 0.f;
  const __half* base = xws;

  auto addrow = [&](int r){
    uint2 wv = *(const uint2*)(base + (size_t)r*DIM + sl*4);
    __half2 h0 = *(__half2*)&wv.x, h1 = *(__half2*)&wv.y;
    float2 f0 = __half22float2(h0), f1 = __half22float2(h1);
    ax += f0.x; ay += f0.y; az += f1.x; aw += f1.y;
  };

  int j = half;
  int n0=0,n1=0,n2=0,n3=0;
  if (j + 6 < total){
    n0 = (j==0) ? v : csr_row[o0 + j - 1];
    n1 = csr_row[o0 + j + 1];
    n2 = csr_row[o0 + j + 3];
    n3 = csr_row[o0 + j + 5];
  }
  while (j + 6 < total){
    int m0=n0, m1=n1, m2=n2, m3=n3;
    int jn = j + 8;
    if (jn + 6 < total){                        // prefetch next indices
      n0 = csr_row[o0 + jn - 1];
      n1 = csr_row[o0 + jn + 1];
      n2 = csr_row[o0 + jn + 3];
      n3 = csr_row[o0 + jn + 5];
    }
    addrow(m0); addrow(m1); addrow(m2); addrow(m3);
    j = jn;
  }
  for (; j < total; j += 2){
    int r = (j==0) ? v : csr_row[o0 + j - 1];
    addrow(r);
  }

  ax += __shfl_xor(ax, 32); ay += __shfl_xor(ay, 32);
  az += __shfl_xor(az, 32); aw += __shfl_xor(aw, 32);

  if (half == 0){
    float4 bb = *(const float4*)(b + sl*4);
    float4 res;
    res.x = dv*ax + bb.x; res.y = dv*ay + bb.y;
    res.z = dv*az + bb.z; res.w = dv*aw + bb.w;
    *(float4*)(out + (size_t)v*DIM + sl*4) = res;
  }
}

// c[j] = relu(posts[root]) @ W2[128:256]; cpool = pooled const cols + raw cr[126..127]
__global__ void k_small(const float* __restrict__ posts, const float* __restrict__ W2,
                        const float* __restrict__ conv1_out, const int* __restrict__ rootIdx,
                        float* __restrict__ cvec, float* __restrict__ cpool){
  int j = threadIdx.x;                          // 128 threads
  int root = rootIdx[0];
  __shared__ float pr[DIM];
  __shared__ float cr[DIM];
  pr[j] = fmaxf(posts[(size_t)root*DIM + j], 0.f);
  cr[j] = conv1_out[(size_t)root*DIM + j];
  __syncthreads();
  float s = 0.f;
  #pragma unroll 4
  for (int k = 0; k < DIM; k++) s += pr[k] * W2[(size_t)(DIM + k)*DIM + j];
  cvec[j] = s;
  cpool[j] = (j < 126) ? (cr[j] + cr[j+1] + cr[j+2]) * (1.f/3.f) : cr[j];
}

// ---- conv2 aggregate + relu + fused pooling; writes only cols 126..253 ----
__global__ void k_conv2(const __half* __restrict__ xws, const int* __restrict__ csr_row,
                        const int* __restrict__ off, const int* __restrict__ cnt,
                        const float* __restrict__ dinv, const float* __restrict__ b2,
                        const float* __restrict__ cpool, float* __restrict__ out, int N){
  int wid  = (blockIdx.x*blockDim.x + threadIdx.x) >> 6;
  if (wid >= N) return;
  int lane = threadIdx.x & 63;
  int half = lane >> 5;
  int sl   = lane & 31;
  int v = wid;
  float dv = dinv[v];
  int o0 = off[v], total = cnt[v] + 1;

  float ax = 0.f, ay = 0.f, az = 0.f, aw = 0.f;
  const __half* base = xws;

  auto addrow = [&](int r){
    uint2 wv = *(const uint2*)(base + (size_t)r*DIM + sl*4);
    __half2 h0 = *(__half2*)&wv.x, h1 = *(__half2*)&wv.y;
    float2 f0 = __half22float2(h0), f1 = __half22float2(h1);
    ax += f0.x; ay += f0.y; az += f1.x; aw += f1.y;
  };

  int j = half;
  int n0=0,n1=0,n2=0,n3=0;
  if (j + 6 < total){
    n0 = (j==0) ? v : csr_row[o0 + j - 1];
    n1 = csr_row[o0 + j + 1];
    n2 = csr_row[o0 + j + 3];
    n3 = csr_row[o0 + j + 5];
  }
  while (j + 6 < total){
    int m0=n0, m1=n1, m2=n2, m3=n3;
    int jn = j + 8;
    if (jn + 6 < total){
      n0 = csr_row[o0 + jn - 1];
      n1 = csr_row[o0 + jn + 1];
      n2 = csr_row[o0 + jn + 3];
      n3 = csr_row[o0 + jn + 5];
    }
    addrow(m0); addrow(m1); addrow(m2); addrow(m3);
    j = jn;
  }
  for (; j < total; j += 2){
    int r = (j==0) ? v : csr_row[o0 + j - 1];
    addrow(r);
  }

  ax += __shfl_xor(ax, 32); ay += __shfl_xor(ay, 32);
  az += __shfl_xor(az, 32); aw += __shfl_xor(aw, 32);

  float4 bb = *(const float4*)(b2 + sl*4);
  float o0v = fmaxf(dv*ax + bb.x, 0.f);         // co[4sl+0]
  float o1v = fmaxf(dv*ay + bb.y, 0.f);         // co[4sl+1]
  float o2v = fmaxf(dv*az + bb.z, 0.f);         // co[4sl+2]
  float o3v = fmaxf(dv*aw + bb.w, 0.f);         // co[4sl+3]

  // pooled col 126+t needs co[t-2], co[t-1], co[t]; prev lane supplies co[4sl-2], co[4sl-1]
  float pz = __shfl_up(o2v, 1);
  float pw = __shfl_up(o3v, 1);
  if (sl == 0){ pz = cpool[126]; pw = cpool[127]; }
  const float third = 1.f/3.f;
  float q0 = (pz + pw + o0v) * third;
  float q1 = (pw + o0v + o1v) * third;
  float q2 = (o0v + o1v + o2v) * third;
  float q3 = (o1v + o2v + o3v) * third;

  if (half == 0){
    float* orow = out + (size_t)v*254 + 126 + sl*4;
    *(float2*)(orow)     = make_float2(q0, q1);
    *(float2*)(orow + 2) = make_float2(q2, q3);
  }
}

extern "C" void kernel_launch(void* const* d_in, const int* in_sizes, int n_in,
                              void* d_out, int out_size, void* d_ws, size_t ws_size,
                              hipStream_t stream){
  const float* posts = (const float*)d_in[0];
  const float* W1    = (const float*)d_in[1];
  const float* b1    = (const float*)d_in[2];
  const float* W2    = (const float*)d_in[3];
  const float* b2    = (const float*)d_in[4];
  const int*   eidx  = (const int*)d_in[5];
  const int*   rootI = (const int*)d_in[6];
  int N = in_sizes[0] / DIM;
  int E = in_sizes[5] / 2;
  const int* row = eidx;
  const int* col = eidx + E;

  char* p = (char*)d_ws;
  auto alloc = [&](size_t bytes)->void*{
    void* q = (void*)p; p += (bytes + 255) & ~(size_t)255; return q;
  };
  __half* xw1s  = (__half*)alloc((size_t)N*DIM*2);
  __half* xw2s  = (__half*)alloc((size_t)N*DIM*2);
  float* c1out  = (float*)alloc((size_t)N*DIM*4);
  float* dinv   = (float*)alloc((size_t)N*4);
  float* cvec   = (float*)alloc(DIM*4);
  float* cpool  = (float*)alloc(DIM*4);
  int*   cnt    = (int*)alloc((size_t)N*4);
  int*   off    = (int*)alloc((size_t)N*4);
  int*   cursor = (int*)alloc((size_t)N*4);
  int*   bsum   = (int*)alloc(512*4);
  int*   csrrow = (int*)alloc((size_t)E*4);

  hipMemsetAsync(cnt, 0, (size_t)N*4, stream);

  int nb = (N + 255) / 256;
  k_count<<<(E + 255)/256, 256, 0, stream>>>(col, E, cnt);
  k_scan1<<<nb, 256, 0, stream>>>(cnt, off, bsum, N);
  k_scan2<<<1, 512, 0, stream>>>(bsum, nb);
  k_scan3<<<nb, 256, 0, stream>>>(off, bsum, cnt, cursor, dinv, N);

  int nG = (N + 31) / 32;                       // 3125
  int nS = (E + 511) / 512;                     // 3125
  int nF = (N*63 + 2047) / 2048;                // 3077
  int grid1 = 2 * (nG > nS ? nG : nS);
  int grid2 = 2 * (nG > nF ? nG : nF);

  k_mega1<<<grid1, 256, 0, stream>>>(posts, W1, dinv, xw1s, row, col, E, cursor, csrrow, N, nG);
  k_conv1<<<(N + 3)/4, 256, 0, stream>>>(xw1s, csrrow, off, cnt, dinv, b1, c1out, N);
  k_small<<<1, 128, 0, stream>>>(posts, W2, c1out, rootI, cvec, cpool);
  k_mega2<<<grid2, 256, 0, stream>>>(c1out, W2, cvec, dinv, xw2s, cpool, (float*)d_out, N, nG, nF);
  k_conv2<<<(N + 3)/4, 256, 0, stream>>>(xw2s, csrrow, off, cnt, dinv, b2, cpool,
                                         (float*)d_out, N);
}

// Round 5
// 370.833 us; speedup vs baseline: 1.2052x; 1.2052x over previous
//
#include <hip/hip_runtime.h>
#include <hip/hip_fp16.h>

#define DIM 128

// ---------------- graph build ----------------
// count in-degree AND record each edge's rank within its destination node
__global__ void k_count(const int* __restrict__ col, int E,
                        int* __restrict__ cnt, int* __restrict__ rank){
  int i = blockIdx.x*blockDim.x + threadIdx.x;
  if (i < E) rank[i] = atomicAdd(&cnt[col[i]], 1);
}

__global__ void k_scan1(const int* __restrict__ cnt, int* __restrict__ off,
                        int* __restrict__ bsum, int N){
  __shared__ int s[256];
  int i = blockIdx.x*256 + threadIdx.x;
  int v = (i < N) ? cnt[i] : 0;
  s[threadIdx.x] = v;
  __syncthreads();
  for (int d = 1; d < 256; d <<= 1){
    int t = (threadIdx.x >= d) ? s[threadIdx.x - d] : 0;
    __syncthreads();
    s[threadIdx.x] += t;
    __syncthreads();
  }
  if (i < N) off[i] = s[threadIdx.x] - v;       // exclusive within block
  if (threadIdx.x == 255) bsum[blockIdx.x] = s[255];
}

__global__ void k_scan2(int* __restrict__ bsum, int nb){
  __shared__ int s[512];
  int t = threadIdx.x;
  int v = (t < nb) ? bsum[t] : 0;
  s[t] = v;
  __syncthreads();
  for (int d = 1; d < 512; d <<= 1){
    int x = (t >= d) ? s[t - d] : 0;
    __syncthreads();
    s[t] += x;
    __syncthreads();
  }
  if (t < nb) bsum[t] = s[t] - v;               // exclusive block offsets
}

__global__ void k_scan3(int* __restrict__ off, const int* __restrict__ bsum,
                        const int* __restrict__ cnt, float* __restrict__ dinv, int N){
  int i = blockIdx.x*blockDim.x + threadIdx.x;
  if (i < N){
    off[i] += bsum[i >> 8];
    dinv[i] = rsqrtf((float)(cnt[i] + 1));      // +1 self-loop
  }
}

// atomic-free scatter: position = off[dest] + precomputed rank
__global__ void k_scatter(const int* __restrict__ row, const int* __restrict__ col,
                          const int* __restrict__ rank, const int* __restrict__ off,
                          int* __restrict__ csr_row, int E){
  int e = blockIdx.x*blockDim.x + threadIdx.x;
  if (e < E){
    int c = col[e];
    csr_row[off[c] + rank[e]] = row[e];
  }
}

// ---- GEMM: Yh[N,128](fp16) = dinv[r] * ( (relu?)X[N,128] @ W[128,128] + addvec ) ----
// INH: input is fp16 (c1out) vs f32 (posts)
template<int INH>
__global__ __launch_bounds__(256) void k_gemm(const void* __restrict__ Xv,
                                              const float* __restrict__ W,
                                              const float* __restrict__ addvec,
                                              const float* __restrict__ dinv,
                                              __half* __restrict__ Yh, int N, int doRelu){
  __shared__ float Xs[64][DIM];   // 32 KB
  __shared__ float Ws[64][DIM];   // 32 KB (K-chunked)
  int tx = threadIdx.x & 31;      // 4 output cols
  int ty = threadIdx.x >> 5;      // 8 rows each
  int rb = blockIdx.x * 64;

  #pragma unroll
  for (int i = 0; i < 8; i++){
    int f4 = i*256 + threadIdx.x;               // [0,2048) float4 slots
    int r  = f4 >> 5;
    int cc = (f4 & 31) * 4;
    float4 val = make_float4(0.f, 0.f, 0.f, 0.f);
    if (rb + r < N){
      if (INH){
        uint2 u = *(const uint2*)((const __half*)Xv + (size_t)(rb + r)*DIM + cc);
        float2 f0 = __half22float2(*(__half2*)&u.x);
        float2 f1 = __half22float2(*(__half2*)&u.y);
        val = make_float4(f0.x, f0.y, f1.x, f1.y);
      } else {
        val = *(const float4*)((const float*)Xv + (size_t)(rb + r)*DIM + cc);
      }
    }
    if (doRelu){
      val.x = fmaxf(val.x, 0.f); val.y = fmaxf(val.y, 0.f);
      val.z = fmaxf(val.z, 0.f); val.w = fmaxf(val.w, 0.f);
    }
    *(float4*)(&Xs[r][cc]) = val;
  }

  float acc[8][4];
  #pragma unroll
  for (int r8 = 0; r8 < 8; r8++){ acc[r8][0]=0.f; acc[r8][1]=0.f; acc[r8][2]=0.f; acc[r8][3]=0.f; }

  #pragma unroll
  for (int kc = 0; kc < DIM; kc += 64){
    __syncthreads();
    #pragma unroll
    for (int i = 0; i < 8; i++){
      int f4 = i*256 + threadIdx.x;
      int r  = f4 >> 5;
      int cc = (f4 & 31) * 4;
      *(float4*)(&Ws[r][cc]) = *(const float4*)(W + (size_t)(kc + r)*DIM + cc);
    }
    __syncthreads();
    #pragma unroll 4
    for (int k = 0; k < 64; k++){
      float4 w4 = *(const float4*)(&Ws[k][tx*4]);
      #pragma unroll
      for (int r8 = 0; r8 < 8; r8++){
        float xv = Xs[ty*8 + r8][kc + k];
        acc[r8][0] += xv*w4.x; acc[r8][1] += xv*w4.y;
        acc[r8][2] += xv*w4.z; acc[r8][3] += xv*w4.w;
      }
    }
  }

  float4 av = make_float4(0.f, 0.f, 0.f, 0.f);
  if (addvec) av = *(const float4*)(addvec + tx*4);
  #pragma unroll
  for (int r8 = 0; r8 < 8; r8++){
    int r = rb + ty*8 + r8;
    if (r < N){
      float dv = dinv[r];
      float ox = dv*(acc[r8][0] + av.x), oy = dv*(acc[r8][1] + av.y);
      float oz = dv*(acc[r8][2] + av.z), ow = dv*(acc[r8][3] + av.w);
      __half2 h01 = __floats2half2_rn(ox, oy);
      __half2 h23 = __floats2half2_rn(oz, ow);
      uint2 u = make_uint2(*(unsigned int*)&h01, *(unsigned int*)&h23);
      *(uint2*)(Yh + (size_t)r*DIM + tx*4) = u;
    }
  }
}

// ---- conv1: one wave/node, 2 rows/wave, uint2 gathers; fp16 out + f32 root row ----
__global__ void k_conv1(const __half* __restrict__ xws, const int* __restrict__ csr_row,
                        const int* __restrict__ off, const int* __restrict__ cnt,
                        const float* __restrict__ dinv, const float* __restrict__ b,
                        const int* __restrict__ rootIdx,
                        __half* __restrict__ outh, float* __restrict__ c1root, int N){
  int wid  = (blockIdx.x*blockDim.x + threadIdx.x) >> 6;
  if (wid >= N) return;
  int lane = threadIdx.x & 63;
  int half = lane >> 5;
  int sl   = lane & 31;
  int v = wid;
  float dv = dinv[v];
  int o0 = off[v], total = cnt[v] + 1;          // virtual entry 0 = self

  float ax = 0.f, ay = 0.f, az = 0.f, aw = 0.f;
  const __half* base = xws;

  auto addrow = [&](int r){
    uint2 wv = *(const uint2*)(base + (size_t)r*DIM + sl*4);
    float2 f0 = __half22float2(*(__half2*)&wv.x);
    float2 f1 = __half22float2(*(__half2*)&wv.y);
    ax += f0.x; ay += f0.y; az += f1.x; aw += f1.y;
  };

  int j = half;
  int n0=0,n1=0,n2=0,n3=0;
  if (j + 6 < total){
    n0 = (j==0) ? v : csr_row[o0 + j - 1];
    n1 = csr_row[o0 + j + 1];
    n2 = csr_row[o0 + j + 3];
    n3 = csr_row[o0 + j + 5];
  }
  while (j + 6 < total){
    int m0=n0, m1=n1, m2=n2, m3=n3;
    int jn = j + 8;
    if (jn + 6 < total){                        // prefetch next indices
      n0 = csr_row[o0 + jn - 1];
      n1 = csr_row[o0 + jn + 1];
      n2 = csr_row[o0 + jn + 3];
      n3 = csr_row[o0 + jn + 5];
    }
    addrow(m0); addrow(m1); addrow(m2); addrow(m3);
    j = jn;
  }
  for (; j < total; j += 2){
    int r = (j==0) ? v : csr_row[o0 + j - 1];
    addrow(r);
  }

  ax += __shfl_xor(ax, 32); ay += __shfl_xor(ay, 32);
  az += __shfl_xor(az, 32); aw += __shfl_xor(aw, 32);

  if (half == 0){
    float4 bb = *(const float4*)(b + sl*4);
    float rx = dv*ax + bb.x, ry = dv*ay + bb.y;
    float rz = dv*az + bb.z, rw = dv*aw + bb.w;
    __half2 h01 = __floats2half2_rn(rx, ry);
    __half2 h23 = __floats2half2_rn(rz, rw);
    uint2 u = make_uint2(*(unsigned int*)&h01, *(unsigned int*)&h23);
    *(uint2*)(outh + (size_t)v*DIM + sl*4) = u;
    if (v == rootIdx[0])
      *(float4*)(c1root + sl*4) = make_float4(rx, ry, rz, rw);
  }
}

// cvec[j] = relu(posts[root]) @ W2[128:256]; cpool = pooled const cols + raw cr[126..127]
__global__ void k_small(const float* __restrict__ posts, const float* __restrict__ W2,
                        const float* __restrict__ c1root, const int* __restrict__ rootIdx,
                        float* __restrict__ cvec, float* __restrict__ cpool){
  int j = threadIdx.x;                          // 128 threads
  int root = rootIdx[0];
  __shared__ float pr[DIM];
  __shared__ float cr[DIM];
  pr[j] = fmaxf(posts[(size_t)root*DIM + j], 0.f);
  cr[j] = c1root[j];
  __syncthreads();
  float s = 0.f;
  #pragma unroll 4
  for (int k = 0; k < DIM; k++) s += pr[k] * W2[(size_t)(DIM + k)*DIM + j];
  cvec[j] = s;
  cpool[j] = (j < 126) ? (cr[j] + cr[j+1] + cr[j+2]) * (1.f/3.f) : cr[j];
}

// ---- conv2: aggregate + relu + fused pooling; half 0 writes pooled, half 1 const cols ----
__global__ void k_conv2(const __half* __restrict__ xws, const int* __restrict__ csr_row,
                        const int* __restrict__ off, const int* __restrict__ cnt,
                        const float* __restrict__ dinv, const float* __restrict__ b2,
                        const float* __restrict__ cpool, float* __restrict__ out, int N){
  int wid  = (blockIdx.x*blockDim.x + threadIdx.x) >> 6;
  if (wid >= N) return;
  int lane = threadIdx.x & 63;
  int half = lane >> 5;
  int sl   = lane & 31;
  int v = wid;
  float dv = dinv[v];
  int o0 = off[v], total = cnt[v] + 1;

  float ax = 0.f, ay = 0.f, az = 0.f, aw = 0.f;
  const __half* base = xws;

  auto addrow = [&](int r){
    uint2 wv = *(const uint2*)(base + (size_t)r*DIM + sl*4);
    float2 f0 = __half22float2(*(__half2*)&wv.x);
    float2 f1 = __half22float2(*(__half2*)&wv.y);
    ax += f0.x; ay += f0.y; az += f1.x; aw += f1.y;
  };

  int j = half;
  int n0=0,n1=0,n2=0,n3=0;
  if (j + 6 < total){
    n0 = (j==0) ? v : csr_row[o0 + j - 1];
    n1 = csr_row[o0 + j + 1];
    n2 = csr_row[o0 + j + 3];
    n3 = csr_row[o0 + j + 5];
  }
  while (j + 6 < total){
    int m0=n0, m1=n1, m2=n2, m3=n3;
    int jn = j + 8;
    if (jn + 6 < total){
      n0 = csr_row[o0 + jn - 1];
      n1 = csr_row[o0 + jn + 1];
      n2 = csr_row[o0 + jn + 3];
      n3 = csr_row[o0 + jn + 5];
    }
    addrow(m0); addrow(m1); addrow(m2); addrow(m3);
    j = jn;
  }
  for (; j < total; j += 2){
    int r = (j==0) ? v : csr_row[o0 + j - 1];
    addrow(r);
  }

  ax += __shfl_xor(ax, 32); ay += __shfl_xor(ay, 32);
  az += __shfl_xor(az, 32); aw += __shfl_xor(aw, 32);

  float4 bb = *(const float4*)(b2 + sl*4);
  float o0v = fmaxf(dv*ax + bb.x, 0.f);         // co[4sl+0]
  float o1v = fmaxf(dv*ay + bb.y, 0.f);         // co[4sl+1]
  float o2v = fmaxf(dv*az + bb.z, 0.f);         // co[4sl+2]
  float o3v = fmaxf(dv*aw + bb.w, 0.f);         // co[4sl+3]

  // pooled col 126+t needs co[t-2..t]; prev lane supplies co[4sl-2], co[4sl-1]
  float pz = __shfl_up(o2v, 1);
  float pw = __shfl_up(o3v, 1);
  if (sl == 0){ pz = cpool[126]; pw = cpool[127]; }
  const float third = 1.f/3.f;
  float q0 = (pz + pw + o0v) * third;
  float q1 = (pw + o0v + o1v) * third;
  float q2 = (o0v + o1v + o2v) * third;
  float q3 = (o1v + o2v + o3v) * third;

  float* orow = out + (size_t)v*254;
  if (half == 0){
    *(float2*)(orow + 126 + sl*4)     = make_float2(q0, q1);
    *(float2*)(orow + 126 + sl*4 + 2) = make_float2(q2, q3);
  } else {
    if (sl < 31) *(float4*)(orow + sl*4) = *(const float4*)(cpool + sl*4);
    else         *(float2*)(orow + 124)  = *(const float2*)(cpool + 124);
  }
}

extern "C" void kernel_launch(void* const* d_in, const int* in_sizes, int n_in,
                              void* d_out, int out_size, void* d_ws, size_t ws_size,
                              hipStream_t stream){
  const float* posts = (const float*)d_in[0];
  const float* W1    = (const float*)d_in[1];
  const float* b1    = (const float*)d_in[2];
  const float* W2    = (const float*)d_in[3];
  const float* b2    = (const float*)d_in[4];
  const int*   eidx  = (const int*)d_in[5];
  const int*   rootI = (const int*)d_in[6];
  int N = in_sizes[0] / DIM;
  int E = in_sizes[5] / 2;
  const int* row = eidx;
  const int* col = eidx + E;

  char* p = (char*)d_ws;
  auto alloc = [&](size_t bytes)->void*{
    void* q = (void*)p; p += (bytes + 255) & ~(size_t)255; return q;
  };
  __half* xw1s  = (__half*)alloc((size_t)N*DIM*2);
  __half* xw2s  = (__half*)alloc((size_t)N*DIM*2);
  __half* c1h   = (__half*)alloc((size_t)N*DIM*2);
  float* dinv   = (float*)alloc((size_t)N*4);
  float* c1root = (float*)alloc(DIM*4);
  float* cvec   = (float*)alloc(DIM*4);
  float* cpool  = (float*)alloc(DIM*4);
  int*   cnt    = (int*)alloc((size_t)N*4);
  int*   off    = (int*)alloc((size_t)N*4);
  int*   rank   = (int*)alloc((size_t)E*4);
  int*   bsum   = (int*)alloc(512*4);
  int*   csrrow = (int*)alloc((size_t)E*4);

  hipMemsetAsync(cnt, 0, (size_t)N*4, stream);

  int nb = (N + 255) / 256;
  k_count  <<<(E + 255)/256, 256, 0, stream>>>(col, E, cnt, rank);
  k_scan1  <<<nb, 256, 0, stream>>>(cnt, off, bsum, N);
  k_scan2  <<<1, 512, 0, stream>>>(bsum, nb);
  k_scan3  <<<nb, 256, 0, stream>>>(off, bsum, cnt, dinv, N);
  k_scatter<<<(E + 255)/256, 256, 0, stream>>>(row, col, rank, off, csrrow, E);

  k_gemm<0><<<(N + 63)/64, 256, 0, stream>>>(posts, W1, nullptr, dinv, xw1s, N, 0);
  k_conv1<<<(N + 3)/4, 256, 0, stream>>>(xw1s, csrrow, off, cnt, dinv, b1, rootI,
                                         c1h, c1root, N);
  k_small<<<1, 128, 0, stream>>>(posts, W2, c1root, rootI, cvec, cpool);
  k_gemm<1><<<(N + 63)/64, 256, 0, stream>>>(c1h, W2, cvec, dinv, xw2s, N, 1);
  k_conv2<<<(N + 3)/4, 256, 0, stream>>>(xw2s, csrrow, off, cnt, dinv, b2, cpool,
                                         (float*)d_out, N);
}